// Round 14
// baseline (169.256 us; speedup 1.0000x reference)
//
#include <hip/hip_runtime.h>

// SKA3D: x [B=2, C=64, D=64, H=64, W=64] fp32; w [B=2, G=8, 27, D, H, W] fp32
// out[b,c,d,h,w] = sum_k x[b,c,(d+di)%64,(h+hi)%64,(w+wi)%64] * w[b,c/8,k,d,h,w]
//
// R14 = R9 (champion 156.3 us: 4-wave block, 2 ch/wave, 4-slot d-ring 48 KB,
// DPP W-halos, b128-only LDS reads, wk[27] single-buffered monolithic at loop
// end, raw s_barrier + counted vmcnt, nontemporal stores, waves_per_eu(2,3))
// + L2 TOUCH-prefetch of wk(d+2):
//  - every register-level wk double-buffer attempt spilled (R6/R7/R10/R11).
//    Instead: 2 asm global_load_dword per thread per iter walk all 432
//    64B-lines of wk(d+2)'s region (27 taps x 1KB) TWO iters ahead (~1600 cy).
//    LOADW(d+1) then hits L2 (~200 cy) instead of HBM (~900 cy) -> the
//    per-iter first-use stall disappears. HBM bytes unchanged (same lines).
//  - dummy dest pinned in a kernel-lifetime VGPR via "+v" (never read ->
//    compiler inserts no waitcnt; hardware clobber harmless). Touch is
//    exec-uniform (line = t mod 432) so every wave issues exactly 2.
//
// Per-wave per-iter VMEM order: stage(3), touch(2), stores(2), wk(27).
// [A] vmcnt(31) drains my stage(d+1) (newer: touch 2 + stores 2 + wk 27 = 31).
// [B] s_barrier -> slot d+1 globally ready AND nobody still reads slot (d+2)&3.

#define ND 64
#define NH 64
#define NW 64
#define HW 4096
#define DHW 262144

typedef const __attribute__((address_space(1))) unsigned int* gp_as1;
typedef __attribute__((address_space(3))) unsigned int* lp_as3;
typedef float f32x4 __attribute__((ext_vector_type(4)));

__device__ __forceinline__ float dpp_prev(float v) {   // lane j <- lane (j-1)&15
    int i = __builtin_bit_cast(int, v);
    i = __builtin_amdgcn_update_dpp(i, i, 0x121, 0xF, 0xF, true);  // row_ror:1
    return __builtin_bit_cast(float, i);
}
__device__ __forceinline__ float dpp_next(float v) {   // lane j <- lane (j+1)&15
    int i = __builtin_bit_cast(int, v);
    i = __builtin_amdgcn_update_dpp(i, i, 0x12F, 0xF, 0xF, true);  // row_ror:15
    return __builtin_bit_cast(float, i);
}

__global__ __launch_bounds__(256)
__attribute__((amdgpu_waves_per_eu(2, 3)))
void ska3d_kernel(const float* __restrict__ x,
                  const float* __restrict__ w,
                  float* __restrict__ out) {
    __shared__ float lds[4][8][6][NW];     // [slot][c][r][w] 48 KB

    const int tid  = threadIdx.x;          // 0..255
    const int lane = tid & 63;
    const int wv   = tid >> 6;             // wave id 0..3
    const int w0   = (lane & 15) * 4;      // w strip start
    const int hl   = lane >> 4;            // 0..3
    const int c0   = wv * 2;               // this wave's channels

    const int bid = blockIdx.x;
    const int dc  = bid & 7;               // d-chunk (8 planes)
    const int ht  = (bid >> 3) & 15;       // h-tile (4 rows)
    const int g   = (bid >> 7) & 7;
    const int b   = bid >> 10;

    const int d0 = dc * 8;
    const int h0 = ht * 4;
    const int h  = h0 + hl;

    const float* xb  = x + (size_t)(b * 64 + g * 8) * DHW;
    const float* wb  = w + (size_t)(b * 8 + g) * 27 * DHW + h * NW + w0;
    const float* wbb = w + (size_t)(b * 8 + g) * 27 * DHW + h0 * NW;  // block w base
    float* ob = out + (size_t)(b * 64 + g * 8 + c0) * DHW + h * NW + w0;

    // stage plane p: 768 16B-units, 256 threads -> 3 ops/thread
#define STAGE(p) do {                                                          \
        const int slot_ = (p) & 3;                                             \
        const int dd_   = (p) & 63;                                            \
        _Pragma("unroll")                                                      \
        for (int i_ = 0; i_ < 3; ++i_) {                                       \
            const int fid = i_ * 256 + tid;    /* 0..767 */                    \
            const int c_  = fid / 96;                                          \
            const int rm_ = fid - c_ * 96;                                     \
            const int r_  = rm_ >> 4;          /* 0..5 */                      \
            const int ws_ = rm_ & 15;          /* 0..15 */                     \
            const int hh_ = (h0 - 1 + r_) & 63;                                \
            const float* gsrc = xb + (size_t)c_ * DHW + dd_ * HW + hh_ * NW + ws_ * 4; \
            __builtin_amdgcn_global_load_lds((gp_as1)gsrc,                     \
                (lp_as3)&lds[slot_][c_][r_][ws_ * 4], 16, 0, 0);               \
        }                                                                      \
    } while (0)

    // L2-warm all 432 64B-lines of wk(dp)'s region: 27 taps x (4 rows x 256B).
    // Exec-uniform (every lane loads); dest pinned in tdum, never read.
#define TOUCH(dp) do {                                                         \
        _Pragma("unroll")                                                      \
        for (int j_ = 0; j_ < 2; ++j_) {                                       \
            const int t_ = j_ * 256 + tid;                                     \
            const int ln_ = (t_ < 432) ? t_ : (t_ - 432);                      \
            const float* ta_ = wbb + (size_t)(ln_ >> 4) * DHW                  \
                                   + (size_t)(dp) * HW + (ln_ & 15) * 16;      \
            asm volatile("global_load_dword %0, %1, off"                       \
                         : "+v"(tdum) : "v"(ta_) : "memory");                  \
        }                                                                      \
    } while (0)

#define LOADW(dp) do {                                                         \
        const float* wp_ = wb + (size_t)(dp) * HW;                             \
        _Pragma("unroll")                                                      \
        for (int k_ = 0; k_ < 27; ++k_)                                        \
            wk[k_] = *(const float4*)(wp_ + (size_t)k_ * DHW);                 \
    } while (0)

    float4 wk[27];
    float tdum = 0.f;                      // touch sink, pinned for kernel life

    // prologue: planes d0-1..d0+1 staged; touch wk(d0+1); wk(d0); full drain
    STAGE(d0 - 1);
    STAGE(d0);
    STAGE(d0 + 1);
    TOUCH(d0 + 1);
    LOADW(d0);
    asm volatile("s_waitcnt vmcnt(0)" ::: "memory");

#pragma unroll 1
    for (int i = 0; i < 8; ++i) {
        const int d = d0 + i;

        // [A] drain my stage(d+1); newer ops = touch 2 + stores 2 + wk 27 = 31
        asm volatile("s_waitcnt vmcnt(31)" ::: "memory");
        // [B] all waves' stage(d+1) done; all waves done reading slot (d+2)&3
        asm volatile("s_barrier" ::: "memory");

        // [C] prefetch plane d+2 into slot (d+2)&3 (disjoint from d-1,d,d+1)
        if (i < 7) STAGE(d + 2);

        // [T] L2-warm wk(d+2) (clamped at chunk end; re-touch is harmless,
        //     keeps per-wave vmcnt accounting uniform)
        const int dpt = d0 + ((i + 2 < 8) ? (i + 2) : 7);
        TOUCH(dpt);

        // [D] compute plane d: one b128 LDS read per (di,hi,cc); halos via DPP
        float acc[2][4];
#pragma unroll
        for (int cc = 0; cc < 2; ++cc)
            acc[cc][0] = acc[cc][1] = acc[cc][2] = acc[cc][3] = 0.f;

#pragma unroll
        for (int di = -1; di <= 1; ++di) {
            const int slot = (d + di) & 3;
#pragma unroll
            for (int hi = -1; hi <= 1; ++hi) {
                const int r  = hl + hi + 1;            // 0..5
                const int kb = (di + 1) * 9 + (hi + 1) * 3;
#pragma unroll
                for (int cc = 0; cc < 2; ++cc) {
                    const float* row = &lds[slot][c0 + cc][r][0];
                    const float4 xv = *(const float4*)(row + w0);
                    const float  xm = dpp_prev(xv.w);   // x[w0-1] (circular)
                    const float  xp = dpp_next(xv.x);   // x[w0+4] (circular)
                    const float4 wa = wk[kb], wm = wk[kb + 1], wc = wk[kb + 2];
                    acc[cc][0] += wa.x * xm;    acc[cc][1] += wa.y * xv.x;
                    acc[cc][2] += wa.z * xv.y;  acc[cc][3] += wa.w * xv.z;
                    acc[cc][0] += wm.x * xv.x;  acc[cc][1] += wm.y * xv.y;
                    acc[cc][2] += wm.z * xv.z;  acc[cc][3] += wm.w * xv.w;
                    acc[cc][0] += wc.x * xv.y;  acc[cc][1] += wc.y * xv.z;
                    acc[cc][2] += wc.z * xv.w;  acc[cc][3] += wc.w * xp;
                }
            }
        }

        // [E] nontemporal stores (out is never re-read) — BEFORE LOADW
#pragma unroll
        for (int cc = 0; cc < 2; ++cc) {
            f32x4 v;
            v.x = acc[cc][0]; v.y = acc[cc][1]; v.z = acc[cc][2]; v.w = acc[cc][3];
            __builtin_nontemporal_store(v,
                (f32x4*)(ob + (size_t)cc * DHW + (size_t)d * HW));
        }

        // [F] wk(d+1) last; fence forbids hoisting the 27-load batch upward
        //     (hoist doubles wk live range -> spill: R6/R7/R10/R11 lesson)
        __builtin_amdgcn_sched_barrier(0);
        if (i < 7) LOADW(d + 1);
    }

    // keep the touch sink allocated to kernel end (never read by hardware path)
    asm volatile("" :: "v"(tdum));
}

extern "C" void kernel_launch(void* const* d_in, const int* in_sizes, int n_in,
                              void* d_out, int out_size, void* d_ws, size_t ws_size,
                              hipStream_t stream) {
    const float* x = (const float*)d_in[0];
    const float* w = (const float*)d_in[1];
    float* out = (float*)d_out;
    // grid: b(2) x g(8) x h-tiles(16) x d-chunks(8) = 2048 blocks of 256
    dim3 grid(2048);
    dim3 block(256);
    hipLaunchKernelGGL(ska3d_kernel, grid, block, 0, stream, x, w, out);
}

// Round 15
// 156.255 us; speedup vs baseline: 1.0832x; 1.0832x over previous
//
#include <hip/hip_runtime.h>

// SKA3D: x [B=2, C=64, D=64, H=64, W=64] fp32; w [B=2, G=8, 27, D, H, W] fp32
// out[b,c,d,h,w] = sum_k x[b,c,(d+di)%64,(h+hi)%64,(w+wi)%64] * w[b,c/8,k,d,h,w]
//
// R15 = exact revert to R9 (champion, 156.3 us). Final form:
//  - 4-wave block, 2 ch/wave; 4-slot d-sliding LDS ring [slot][c][r][w] 48 KB
//  - staging via global_load_lds width=16, linear LDS dest
//  - b128-only LDS reads; W-halos via DPP row_ror on the VALU pipe
//    (scalar b32 halos were an 8-way bank conflict — R5->R9 was +9%)
//  - wk[27] single-buffered, loaded MONOLITHICALLY at loop end (any other
//    shape — chunked reload, pre-store placement, touch-prefetch — spilled
//    or regressed: R6/R7/R10/R11/R14)
//  - raw s_barrier + counted vmcnt (no __syncthreads vmcnt(0) drain)
//  - nontemporal output stores; amdgpu_waves_per_eu(2,3)
// Equilibrium: ~170-200 VGPR/wave -> 3 waves/SIMD; 48 KB x 3 blocks = 144 KB
// ~ LDS budget. 12 waves/CU. Effective ~4.5-5 TB/s on a ~694 MB HBM floor.
//
// Per-wave per-iter VMEM order: stage(3), stores(2), wk(27).
// [A] vmcnt(29) drains my stage(d+1) (newer: 2 stores + 27 wk = 29).
// [B] s_barrier -> slot d+1 globally ready AND nobody still reads slot (d+2)&3.

#define ND 64
#define NH 64
#define NW 64
#define HW 4096
#define DHW 262144

typedef const __attribute__((address_space(1))) unsigned int* gp_as1;
typedef __attribute__((address_space(3))) unsigned int* lp_as3;
typedef float f32x4 __attribute__((ext_vector_type(4)));

__device__ __forceinline__ float dpp_prev(float v) {   // lane j <- lane (j-1)&15
    int i = __builtin_bit_cast(int, v);
    i = __builtin_amdgcn_update_dpp(i, i, 0x121, 0xF, 0xF, true);  // row_ror:1
    return __builtin_bit_cast(float, i);
}
__device__ __forceinline__ float dpp_next(float v) {   // lane j <- lane (j+1)&15
    int i = __builtin_bit_cast(int, v);
    i = __builtin_amdgcn_update_dpp(i, i, 0x12F, 0xF, 0xF, true);  // row_ror:15
    return __builtin_bit_cast(float, i);
}

__global__ __launch_bounds__(256)
__attribute__((amdgpu_waves_per_eu(2, 3)))
void ska3d_kernel(const float* __restrict__ x,
                  const float* __restrict__ w,
                  float* __restrict__ out) {
    __shared__ float lds[4][8][6][NW];     // [slot][c][r][w] 48 KB

    const int tid  = threadIdx.x;          // 0..255
    const int lane = tid & 63;
    const int wv   = tid >> 6;             // wave id 0..3
    const int w0   = (lane & 15) * 4;      // w strip start
    const int hl   = lane >> 4;            // 0..3
    const int c0   = wv * 2;               // this wave's channels

    const int bid = blockIdx.x;
    const int dc  = bid & 7;               // d-chunk (8 planes)
    const int ht  = (bid >> 3) & 15;       // h-tile (4 rows)
    const int g   = (bid >> 7) & 7;
    const int b   = bid >> 10;

    const int d0 = dc * 8;
    const int h0 = ht * 4;
    const int h  = h0 + hl;

    const float* xb = x + (size_t)(b * 64 + g * 8) * DHW;
    const float* wb = w + (size_t)(b * 8 + g) * 27 * DHW + h * NW + w0;
    float* ob = out + (size_t)(b * 64 + g * 8 + c0) * DHW + h * NW + w0;

    // stage plane p: 768 16B-units, 256 threads -> 3 ops/thread
#define STAGE(p) do {                                                          \
        const int slot_ = (p) & 3;                                             \
        const int dd_   = (p) & 63;                                            \
        _Pragma("unroll")                                                      \
        for (int i_ = 0; i_ < 3; ++i_) {                                       \
            const int fid = i_ * 256 + tid;    /* 0..767 */                    \
            const int c_  = fid / 96;                                          \
            const int rm_ = fid - c_ * 96;                                     \
            const int r_  = rm_ >> 4;          /* 0..5 */                      \
            const int ws_ = rm_ & 15;          /* 0..15 */                     \
            const int hh_ = (h0 - 1 + r_) & 63;                                \
            const float* gsrc = xb + (size_t)c_ * DHW + dd_ * HW + hh_ * NW + ws_ * 4; \
            __builtin_amdgcn_global_load_lds((gp_as1)gsrc,                     \
                (lp_as3)&lds[slot_][c_][r_][ws_ * 4], 16, 0, 0);               \
        }                                                                      \
    } while (0)

#define LOADW(dp) do {                                                         \
        const float* wp_ = wb + (size_t)(dp) * HW;                             \
        _Pragma("unroll")                                                      \
        for (int k_ = 0; k_ < 27; ++k_)                                        \
            wk[k_] = *(const float4*)(wp_ + (size_t)k_ * DHW);                 \
    } while (0)

    float4 wk[27];

    // prologue: planes d0-1, d0, d0+1 staged; wk(d0) loaded; full drain
    STAGE(d0 - 1);
    STAGE(d0);
    STAGE(d0 + 1);
    LOADW(d0);
    asm volatile("s_waitcnt vmcnt(0)" ::: "memory");

#pragma unroll 1
    for (int i = 0; i < 8; ++i) {
        const int d = d0 + i;

        // [A] drain my stage(d+1); newer ops = 2 stores + 27 wk = 29
        asm volatile("s_waitcnt vmcnt(29)" ::: "memory");
        // [B] all waves' stage(d+1) done; all waves done reading slot (d+2)&3
        asm volatile("s_barrier" ::: "memory");

        // [C] prefetch plane d+2 into slot (d+2)&3 (disjoint from d-1,d,d+1)
        if (i < 7) STAGE(d + 2);

        // [D] compute plane d: one b128 LDS read per (di,hi,cc); halos via DPP
        float acc[2][4];
#pragma unroll
        for (int cc = 0; cc < 2; ++cc)
            acc[cc][0] = acc[cc][1] = acc[cc][2] = acc[cc][3] = 0.f;

#pragma unroll
        for (int di = -1; di <= 1; ++di) {
            const int slot = (d + di) & 3;
#pragma unroll
            for (int hi = -1; hi <= 1; ++hi) {
                const int r  = hl + hi + 1;            // 0..5
                const int kb = (di + 1) * 9 + (hi + 1) * 3;
#pragma unroll
                for (int cc = 0; cc < 2; ++cc) {
                    const float* row = &lds[slot][c0 + cc][r][0];
                    const float4 xv = *(const float4*)(row + w0);
                    const float  xm = dpp_prev(xv.w);   // x[w0-1] (circular)
                    const float  xp = dpp_next(xv.x);   // x[w0+4] (circular)
                    const float4 wa = wk[kb], wm = wk[kb + 1], wc = wk[kb + 2];
                    acc[cc][0] += wa.x * xm;    acc[cc][1] += wa.y * xv.x;
                    acc[cc][2] += wa.z * xv.y;  acc[cc][3] += wa.w * xv.z;
                    acc[cc][0] += wm.x * xv.x;  acc[cc][1] += wm.y * xv.y;
                    acc[cc][2] += wm.z * xv.z;  acc[cc][3] += wm.w * xv.w;
                    acc[cc][0] += wc.x * xv.y;  acc[cc][1] += wc.y * xv.z;
                    acc[cc][2] += wc.z * xv.w;  acc[cc][3] += wc.w * xp;
                }
            }
        }

        // [E] nontemporal stores (out is never re-read)
#pragma unroll
        for (int cc = 0; cc < 2; ++cc) {
            f32x4 v;
            v.x = acc[cc][0]; v.y = acc[cc][1]; v.z = acc[cc][2]; v.w = acc[cc][3];
            __builtin_nontemporal_store(v,
                (f32x4*)(ob + (size_t)cc * DHW + (size_t)d * HW));
        }

        // [F] wk(d+1) for next iteration (whole, at loop end — proven shape)
        if (i < 7) LOADW(d + 1);
    }
}

extern "C" void kernel_launch(void* const* d_in, const int* in_sizes, int n_in,
                              void* d_out, int out_size, void* d_ws, size_t ws_size,
                              hipStream_t stream) {
    const float* x = (const float*)d_in[0];
    const float* w = (const float*)d_in[1];
    float* out = (float*)d_out;
    // grid: b(2) x g(8) x h-tiles(16) x d-chunks(8) = 2048 blocks of 256
    dim3 grid(2048);
    dim3 block(256);
    hipLaunchKernelGGL(ska3d_kernel, grid, block, 0, stream, x, w, out);
}